// Round 8
// baseline (557.733 us; speedup 1.0000x reference)
//
#include <hip/hip_runtime.h>

#define BATCH 32
#define SEQ   512
#define EMBD  128
#define HEADS 8
#define HD    16
#define ROWS  (BATCH*SEQ)      // 16384
#define GR    32               // rows per GEMM block
#define NT32  (ROWS/GR)        // 512

// ============================================================
// LDS-free GEMM: block = 32 rows, 256 threads, thread owns 4r x 4c.
// ============================================================
__device__ __forceinline__ void gemm_nolds(const float* __restrict__ A,
                                           const float* __restrict__ W,
                                           int rowBase, int tid,
                                           float acc[4][4])
{
    const int r0 = (tid >> 5) * 4;     // 8 groups x 4 rows
    const int c0 = (tid & 31) * 4;
    const float* Ab = A + (size_t)(rowBase + r0) * EMBD;
    for (int e0 = 0; e0 < EMBD; e0 += 4) {
        float4 a[4];
        #pragma unroll
        for (int r = 0; r < 4; ++r)
            a[r] = *(const float4*)(Ab + r*EMBD + e0);
        float4 w[4];
        #pragma unroll
        for (int j = 0; j < 4; ++j)
            w[j] = *(const float4*)(W + (e0+j)*EMBD + c0);
        #pragma unroll
        for (int r = 0; r < 4; ++r) {
            acc[r][0] += a[r].x*w[0].x + a[r].y*w[1].x + a[r].z*w[2].x + a[r].w*w[3].x;
            acc[r][1] += a[r].x*w[0].y + a[r].y*w[1].y + a[r].z*w[2].y + a[r].w*w[3].y;
            acc[r][2] += a[r].x*w[0].z + a[r].y*w[1].z + a[r].z*w[2].z + a[r].w*w[3].z;
            acc[r][3] += a[r].x*w[0].w + a[r].y*w[1].w + a[r].z*w[2].w + a[r].w*w[3].w;
        }
    }
}

__device__ __forceinline__ void store_nolds(float* __restrict__ out,
                                            int rowBase, int tid,
                                            float acc[4][4])
{
    const int r0 = (tid >> 5) * 4;
    const int c0 = (tid & 31) * 4;
    #pragma unroll
    for (int r = 0; r < 4; ++r)
        *(float4*)(out + (size_t)(rowBase + r0 + r)*EMBD + c0) =
            make_float4(acc[r][0], acc[r][1], acc[r][2], acc[r][3]);
}

// ============================================================
// All 8 projection GEMMs in one launch. blockIdx.y = job:
//   0: Q  = q1@Wqf + ln@Wql + fg@Wqfe + lg@Wqle ; 1..4: K, V, Ke, Ve
// ============================================================
__global__ __launch_bounds__(256) void proj_all_kernel(
    const float* __restrict__ nodes, const float* __restrict__ graph,
    const float* __restrict__ q1,    const float* __restrict__ fg,
    const float* __restrict__ ln,    const float* __restrict__ lg,
    const float* __restrict__ Wqf,  const float* __restrict__ Wql,
    const float* __restrict__ Wqfe, const float* __restrict__ Wqle,
    const float* __restrict__ Wk,   const float* __restrict__ Wv,
    const float* __restrict__ Wke,  const float* __restrict__ Wve,
    float* __restrict__ Qb, float* __restrict__ Kb, float* __restrict__ Vb,
    float* __restrict__ Keb, float* __restrict__ Veb)
{
    const int tid = threadIdx.x;
    const int rowBase = blockIdx.x * GR;
    const int job = blockIdx.y;
    float acc[4][4];
    #pragma unroll
    for (int r = 0; r < 4; ++r)
        #pragma unroll
        for (int c = 0; c < 4; ++c) acc[r][c] = 0.f;
    if (job == 0) {
        gemm_nolds(q1, Wqf,  rowBase, tid, acc);
        gemm_nolds(ln, Wql,  rowBase, tid, acc);
        gemm_nolds(fg, Wqfe, rowBase, tid, acc);
        gemm_nolds(lg, Wqle, rowBase, tid, acc);
        store_nolds(Qb, rowBase, tid, acc);
    } else if (job == 1) {
        gemm_nolds(nodes, Wk, rowBase, tid, acc);
        store_nolds(Kb, rowBase, tid, acc);
    } else if (job == 2) {
        gemm_nolds(nodes, Wv, rowBase, tid, acc);
        store_nolds(Vb, rowBase, tid, acc);
    } else if (job == 3) {
        gemm_nolds(graph, Wke, rowBase, tid, acc);
        store_nolds(Keb, rowBase, tid, acc);
    } else {
        gemm_nolds(graph, Wve, rowBase, tid, acc);
        store_nolds(Veb, rowBase, tid, acc);
    }
}

// ============================================================
// combine: mh = out1@Wc1 + out2@Wc2 + (b1 + b2)
// ============================================================
__global__ __launch_bounds__(256) void combine_kernel(
    const float* __restrict__ A0, const float* __restrict__ W0,
    const float* __restrict__ A1, const float* __restrict__ W1,
    const float* __restrict__ b0, const float* __restrict__ b1,
    float* __restrict__ out)
{
    const int tid = threadIdx.x;
    const int rowBase = blockIdx.x * GR;
    const int c0 = (tid & 31) * 4;
    float acc[4][4];
    #pragma unroll
    for (int c = 0; c < 4; ++c) {
        float bv = b0[c0+c] + b1[c0+c];
        #pragma unroll
        for (int r = 0; r < 4; ++r) acc[r][c] = bv;
    }
    gemm_nolds(A0, W0, rowBase, tid, acc);
    gemm_nolds(A1, W1, rowBase, tid, acc);
    store_nolds(out, rowBase, tid, acc);
}

// ============================================================
// dual attention v4: blockIdx = j*32 + b (XCD = b%8 -> L2 locality).
// 512 threads = 2 heads x 256 threads; thread owns rows {r, r+256}
// -> one K/V LDS read feeds 64 FMAs (2 rows). 128 KB LDS, 8 waves/CU.
// Mask: full 64 B lines per 16-m chunk, for both rows.
// ============================================================
__global__ __launch_bounds__(512) void attn_kernel(
    const float* __restrict__ Qm, const float* __restrict__ Km,
    const float* __restrict__ Vm, const float* __restrict__ Kem,
    const float* __restrict__ Vem, const float* __restrict__ mask,
    float* __restrict__ out1, float* __restrict__ out2)
{
    extern __shared__ float smem[];
    float4* sK0 = (float4*)smem;     // 2048 f4 each (512 x 16 f32)
    float4* sV0 = sK0 + 2048;
    float4* sK1 = sV0 + 2048;
    float4* sV1 = sK1 + 2048;
    const int tid  = threadIdx.x;
    const int b    = blockIdx.x & 31;      // XCD = b % 8 for all j
    const int j    = blockIdx.x >> 5;      // 0..7
    const int type = j & 1;
    const int hp   = j >> 1;               // 0..3
    const float* K = type ? Kem : Km;
    const float* V = type ? Vem : Vm;
    float* outp    = type ? out2 : out1;
    const int h0 = hp * 2;
    {
        const float4* K4 = (const float4*)K;
        const float4* V4 = (const float4*)V;
        const int b0 = b*(SEQ*EMBD/4) + h0*(HD/4);
        #pragma unroll
        for (int k = 0; k < 4; ++k) {
            int i = tid + k*512;           // [0, 2048)
            int m = i >> 2, jj = i & 3;
            int g0 = b0 + m*(EMBD/4) + jj;
            sK0[i] = K4[g0];
            sV0[i] = V4[g0];
            sK1[i] = K4[g0 + 4];           // head1 = +16 floats
            sV1[i] = V4[g0 + 4];
        }
    }
    __syncthreads();

    const int head = tid >> 8;             // wave-uniform (waves 0-3 / 4-7)
    const int r0   = tid & 255;            // rows r0 and r0+256
    const float4* sK = head ? sK1 : sK0;
    const float4* sV = head ? sV1 : sV0;

    float q[2][16];
    {
        const float4* Q4 = (const float4*)Qm;
        #pragma unroll
        for (int rr = 0; rr < 2; ++rr) {
            const int qb = b*(SEQ*EMBD/4) + (r0 + rr*256)*(EMBD/4) + (h0+head)*(HD/4);
            #pragma unroll
            for (int jj = 0; jj < 4; ++jj)
                *(float4*)&q[rr][jj*4] = Q4[qb + jj];
        }
    }
    const float4* mrowA = (const float4*)(mask + ((size_t)b*SEQ + r0)*SEQ);
    const float4* mrowB = (const float4*)(mask + ((size_t)b*SEQ + r0 + 256)*SEQ);

    float l0 = 0.f, l1 = 0.f;
    float acc0[16], acc1[16];
    #pragma unroll
    for (int d = 0; d < 16; ++d) { acc0[d] = 0.f; acc1[d] = 0.f; }

    for (int mc = 0; mc < SEQ/16; ++mc) {
        // one full 64 B mask line per row, consumed entirely
        float4 mkA[4], mkB[4];
        #pragma unroll
        for (int k = 0; k < 4; ++k) { mkA[k] = mrowA[mc*4 + k]; mkB[k] = mrowB[mc*4 + k]; }
        const float* mfA = (const float*)mkA;
        const float* mfB = (const float*)mkB;
        #pragma unroll
        for (int u = 0; u < 16; ++u) {
            const int m = mc*16 + u;
            float4 k0 = sK[m*4+0], k1 = sK[m*4+1], k2 = sK[m*4+2], k3 = sK[m*4+3];
            float s0 = q[0][0]*k0.x + q[0][1]*k0.y + q[0][2]*k0.z + q[0][3]*k0.w
                     + q[0][4]*k1.x + q[0][5]*k1.y + q[0][6]*k1.z + q[0][7]*k1.w
                     + q[0][8]*k2.x + q[0][9]*k2.y + q[0][10]*k2.z + q[0][11]*k2.w
                     + q[0][12]*k3.x + q[0][13]*k3.y + q[0][14]*k3.z + q[0][15]*k3.w;
            float s1 = q[1][0]*k0.x + q[1][1]*k0.y + q[1][2]*k0.z + q[1][3]*k0.w
                     + q[1][4]*k1.x + q[1][5]*k1.y + q[1][6]*k1.z + q[1][7]*k1.w
                     + q[1][8]*k2.x + q[1][9]*k2.y + q[1][10]*k2.z + q[1][11]*k2.w
                     + q[1][12]*k3.x + q[1][13]*k3.y + q[1][14]*k3.z + q[1][15]*k3.w;
            float p0 = __expf(s0*0.25f + mfA[u]);
            float p1 = __expf(s1*0.25f + mfB[u]);
            l0 += p0; l1 += p1;
            float4 v0 = sV[m*4+0], v1 = sV[m*4+1], v2 = sV[m*4+2], v3 = sV[m*4+3];
            acc0[0]+=p0*v0.x;  acc0[1]+=p0*v0.y;  acc0[2]+=p0*v0.z;  acc0[3]+=p0*v0.w;
            acc0[4]+=p0*v1.x;  acc0[5]+=p0*v1.y;  acc0[6]+=p0*v1.z;  acc0[7]+=p0*v1.w;
            acc0[8]+=p0*v2.x;  acc0[9]+=p0*v2.y;  acc0[10]+=p0*v2.z; acc0[11]+=p0*v2.w;
            acc0[12]+=p0*v3.x; acc0[13]+=p0*v3.y; acc0[14]+=p0*v3.z; acc0[15]+=p0*v3.w;
            acc1[0]+=p1*v0.x;  acc1[1]+=p1*v0.y;  acc1[2]+=p1*v0.z;  acc1[3]+=p1*v0.w;
            acc1[4]+=p1*v1.x;  acc1[5]+=p1*v1.y;  acc1[6]+=p1*v1.z;  acc1[7]+=p1*v1.w;
            acc1[8]+=p1*v2.x;  acc1[9]+=p1*v2.y;  acc1[10]+=p1*v2.z; acc1[11]+=p1*v2.w;
            acc1[12]+=p1*v3.x; acc1[13]+=p1*v3.y; acc1[14]+=p1*v3.z; acc1[15]+=p1*v3.w;
        }
    }
    float4* o4 = (float4*)outp;
    const float i0 = 1.f / l0;
    const float i1 = 1.f / l1;
    {
        const int ob = b*(SEQ*EMBD/4) + r0*(EMBD/4) + (h0+head)*(HD/4);
        #pragma unroll
        for (int jj = 0; jj < 4; ++jj)
            o4[ob + jj] = make_float4(acc0[jj*4]*i0, acc0[jj*4+1]*i0,
                                      acc0[jj*4+2]*i0, acc0[jj*4+3]*i0);
    }
    {
        const int ob = b*(SEQ*EMBD/4) + (r0+256)*(EMBD/4) + (h0+head)*(HD/4);
        #pragma unroll
        for (int jj = 0; jj < 4; ++jj)
            o4[ob + jj] = make_float4(acc1[jj*4]*i1, acc1[jj*4+1]*i1,
                                      acc1[jj*4+2]*i1, acc1[jj*4+3]*i1);
    }
}

// ============================================================
// final v4: scores in REGISTERS, wave-local softmax; MT=128 tile,
// 2 m per lane (mg, mg+64) -> 6 LDS reads / 32 FMA per e0-step.
// Block = 512 threads (8 waves x 4 rows), LDS 80 KB -> 2 blocks/CU.
// blockIdx = tile*32 + b (XCD = b%8).
// ============================================================
#define RB 32
#define MT 128
__global__ __launch_bounds__(512) void final_kernel(
    const float* __restrict__ mh, const float* __restrict__ nodes,
    const float* __restrict__ graph, const float* __restrict__ mask,
    float* __restrict__ out)
{
    extern __shared__ float smem[];
    float4* sShk4 = (float4*)smem;            // MT*EMBD/4 = 4096 f4 (swizzled)
    float*  sMh   = smem + MT*EMBD;           // RB*EMBD = 4096 f
    const int tid  = threadIdx.x;
    const int b    = blockIdx.x & 31;         // XCD = b % 8
    const int row0 = (blockIdx.x >> 5) * RB;
    const int mg = tid & 63;                  // lane: m = mg and mg+64
    const int rg = tid >> 6;                  // wave: 4 rows

    {   // stage mh rows (32 x 128) = 1024 f4
        const float4* mh4 = (const float4*)(mh + ((size_t)b*SEQ + row0)*EMBD);
        ((float4*)sMh)[tid]       = mh4[tid];
        ((float4*)sMh)[tid + 512] = mh4[tid + 512];
    }

    const float4* n4 = (const float4*)nodes;
    const float4* g4 = (const float4*)graph;
    float p[4][8];                            // [row][tile*2 + half]
    float rs[4] = {0.f, 0.f, 0.f, 0.f};

    #pragma unroll
    for (int mt = 0; mt < SEQ/MT; ++mt) {     // 4 tiles
        const int m0 = mt * MT;
        __syncthreads();
        {   // stage shk = nodes+graph tile, XOR-swizzled: 4096 f4, 8/thread
            const int gb = (b*SEQ + m0) * (EMBD/4);
            #pragma unroll
            for (int k = 0; k < 8; ++k) {
                int i = tid + k*512;
                int m = i >> 5, f = i & 31;
                float4 x = n4[gb + m*32 + f];
                float4 y = g4[gb + m*32 + f];
                float4 s4;
                s4.x = x.x + y.x; s4.y = x.y + y.y;
                s4.z = x.z + y.z; s4.w = x.w + y.w;
                sShk4[(m << 5) | (f ^ (m & 31))] = s4;
            }
        }
        __syncthreads();

        float acc[4][2];
        #pragma unroll
        for (int r = 0; r < 4; ++r) { acc[r][0] = 0.f; acc[r][1] = 0.f; }
        const int mA = mg, mB = mg + 64;
        #pragma unroll 8
        for (int e0 = 0; e0 < EMBD; e0 += 4) {
            const int f = e0 >> 2;
            float4 s0 = sShk4[(mA << 5) | (f ^ (mA & 31))];
            float4 s1 = sShk4[(mB << 5) | (f ^ (mB & 31))];
            #pragma unroll
            for (int r = 0; r < 4; ++r) {
                const float* a = &sMh[(rg*4+r)*EMBD + e0];
                acc[r][0] += a[0]*s0.x + a[1]*s0.y + a[2]*s0.z + a[3]*s0.w;
                acc[r][1] += a[0]*s1.x + a[1]*s1.y + a[2]*s1.z + a[3]*s1.w;
            }
        }
        #pragma unroll
        for (int r = 0; r < 4; ++r) {
            const int row = row0 + rg*4 + r;
            const size_t mb = ((size_t)b*SEQ + row)*SEQ + m0;
            #pragma unroll
            for (int h = 0; h < 2; ++h) {
                // tanh(x) = 1 - 2/(e^{2x}+1)
                float x = acc[r][h] * 0.088388347648318447f;   // /sqrt(128)
                float t = 1.f - 2.f / (__expf(2.f*x) + 1.f);
                float sc = 10.f*t + mask[mb + h*64 + mg];
                float pp = __expf(sc);
                p[r][mt*2 + h] = pp;
                rs[r] += pp;
            }
        }
    }

    // wave-local row sums (64-lane butterfly)
    #pragma unroll
    for (int r = 0; r < 4; ++r) {
        float s = rs[r];
        #pragma unroll
        for (int off = 32; off >= 1; off >>= 1) s += __shfl_xor(s, off);
        rs[r] = 1.f / s;
    }

    #pragma unroll
    for (int mt = 0; mt < SEQ/MT; ++mt) {
        #pragma unroll
        for (int r = 0; r < 4; ++r) {
            const int row = row0 + rg*4 + r;
            #pragma unroll
            for (int h = 0; h < 2; ++h)
                out[((size_t)b*SEQ + row)*SEQ + mt*MT + h*64 + mg] =
                    p[r][mt*2 + h] * rs[r];
        }
    }
}

// ============================================================
extern "C" void kernel_launch(void* const* d_in, const int* in_sizes, int n_in,
                              void* d_out, int out_size, void* d_ws, size_t ws_size,
                              hipStream_t stream)
{
    const float* nodes = (const float*)d_in[0];
    const float* graph = (const float*)d_in[1];
    const float* q1    = (const float*)d_in[2];
    const float* fg    = (const float*)d_in[3];
    const float* ln    = (const float*)d_in[4];
    const float* lg    = (const float*)d_in[5];
    const float* mask  = (const float*)d_in[6];
    const float* Wqf   = (const float*)d_in[7];
    const float* Wql   = (const float*)d_in[8];
    const float* Wk    = (const float*)d_in[9];
    const float* Wv    = (const float*)d_in[10];
    const float* Wqfe  = (const float*)d_in[11];
    const float* Wqle  = (const float*)d_in[12];
    const float* Wke   = (const float*)d_in[13];
    const float* Wve   = (const float*)d_in[14];
    const float* Wc1   = (const float*)d_in[15];
    const float* bc1   = (const float*)d_in[16];
    const float* Wc2   = (const float*)d_in[17];
    const float* bc2   = (const float*)d_in[18];

    float* ws = (float*)d_ws;
    const size_t BUF = (size_t)ROWS * EMBD;   // 2,097,152 floats
    float* Qb  = ws;
    float* Kb  = ws + BUF;
    float* Vb  = ws + 2*BUF;
    float* Keb = ws + 3*BUF;
    float* Veb = ws + 4*BUF;
    float* mhb = Qb;                 // Q dead after attention; reuse
    float* o1  = (float*)d_out;      // out1/out2 staged in d_out,
    float* o2  = o1 + BUF;           // consumed by combine before final overwrites

    const int LDS_ATTN  = 4 * SEQ * HD * 4;            // 131072
    const int LDS_FINAL = (MT*EMBD + RB*EMBD) * 4;     // 81920
    hipFuncSetAttribute((const void*)attn_kernel,  hipFuncAttributeMaxDynamicSharedMemorySize, LDS_ATTN);
    hipFuncSetAttribute((const void*)final_kernel, hipFuncAttributeMaxDynamicSharedMemorySize, LDS_FINAL);

    proj_all_kernel<<<dim3(NT32, 5), 256, 0, stream>>>(
        nodes, graph, q1, fg, ln, lg,
        Wqf, Wql, Wqfe, Wqle, Wk, Wv, Wke, Wve,
        Qb, Kb, Vb, Keb, Veb);
    attn_kernel<<<BATCH*8, 512, LDS_ATTN, stream>>>(
        Qb, Kb, Vb, Keb, Veb, mask, o1, o2);
    combine_kernel<<<NT32, 256, 0, stream>>>(
        o1, Wc1, o2, Wc2, bc1, bc2, mhb);
    final_kernel<<<BATCH*(SEQ/RB), 512, LDS_FINAL, stream>>>(
        mhb, nodes, graph, mask, (float*)d_out);
}